// Round 4
// baseline (1080.379 us; speedup 1.0000x reference)
//
#include <hip/hip_runtime.h>
#include <cstdint>
#include <cstddef>

// ---------------------------------------------------------------------------
// EncoderBlock: S=4096, E=2048, H=8192, fp32 in/out, bf16 MFMA internally.
// R7: R6's 256^2 4-phase/K-tile schedule with the serialization removed:
//   - ONE barrier per phase (trailing). Mid-phase barrier + explicit
//     lgkmcnt(0) deleted: compiler emits fine-grained lgkm waits, so MFMA
//     overlaps the LDS-read tail instead of draining it. Ledger: every
//     ds_read in phase p is consumed by phase-p MFMA before the trailing
//     barrier, so staging regions retired in p at p+1-start is race-free.
//   - sched_barrier(0) pinned before each s_barrier (no cross-barrier sink).
//   - stage-issue at phase START (issue-early, T14 principle).
//   - counted vmcnt(6) gate once per K-tile, unchanged (R6 ledger).
//   - V^T projection now split-K x2 (256 WGs, full chip) + row-bias combine.
// ---------------------------------------------------------------------------

constexpr int S = 4096;
constexpr int E = 2048;
constexpr int H = 8192;

typedef __bf16 bf16;
typedef bf16  bf16x8 __attribute__((ext_vector_type(8)));
typedef bf16  bf16x4 __attribute__((ext_vector_type(4)));
typedef float f32x4  __attribute__((ext_vector_type(4)));

typedef __attribute__((address_space(1))) void as1_void;
typedef __attribute__((address_space(3))) void as3_void;

__device__ __forceinline__ void ldg2lds16(const void* g, void* l) {
  __builtin_amdgcn_global_load_lds((as1_void*)g, (as3_void*)l, 16, 0, 0);
}

// ---------------------------------------------------------------------------
// gemm256: C[M,N] = A[M,K] @ Bt[N,K]^T. Tile 256x256, BK=64. Epilogues:
// EPI 0: out bf16 = acc + bias[col]        (merged QK proj)
// EPI 2: out bf16 = acc * scale            (scores)
// EPI 4: out bf16 = relu(acc + bias[col])  (FFN act)
// EPI 6: out f32  = acc (raw partial; dst = kh ? Cf2 : Cf)   (split-K)
// Requires M%256==0, N%256==0, Keff%64==0, Keff/64 >= 2, nwg%8==0.
// ---------------------------------------------------------------------------
template <int EPI, bool SPLITK>
__global__ __launch_bounds__(512, 2)
void gemm256(const bf16* __restrict__ A, int lda,
             const bf16* __restrict__ Bt, int ldb,
             bf16* __restrict__ Cb, float* __restrict__ Cf,
             float* __restrict__ Cf2, int ldc,
             const float* __restrict__ bias,
             int M, int N, int K, float scale)
{
  __shared__ bf16 sA[2][256 * 64];   // 64 KB
  __shared__ bf16 sB[2][256 * 64];   // 64 KB

  const int tid  = threadIdx.x;
  const int lane = tid & 63;
  const int wave = tid >> 6;

  // XCD-chunked swizzle (nwg % 8 == 0 -> bijective)
  const int nbx = gridDim.x;
  const int nwg = nbx * gridDim.y;
  const int bid = blockIdx.y * nbx + blockIdx.x;
  int wg = (bid & 7) * (nwg >> 3) + (bid >> 3);

  int kh = 0;
  if (SPLITK) { const int hw = nwg >> 1; if (wg >= hw) { kh = 1; wg -= hw; } }
  const int ntx  = N >> 8;
  const int m0   = (wg / ntx) * 256;
  const int n0   = (wg % ntx) * 256;
  const int Keff = SPLITK ? (K >> 1) : K;
  if (SPLITK) { const size_t ko = (size_t)kh * Keff; A += ko; Bt += ko; }

  // staging: thread covers row tr (0..63) of a 64-row group, 16B chunk tc.
  // Global chunk XOR-swizzled by (row&7); LDS stays linear (gload_lds rule).
  const int tr  = tid >> 3;
  const int tc  = tid & 7;
  const int gsw = (tc ^ (tr & 7)) * 8;
  const bf16* gA = A  + (size_t)(m0 + tr) * lda + gsw;
  const bf16* gB = Bt + (size_t)(n0 + tr) * ldb + gsw;
  const size_t a64 = (size_t)64 * lda;
  const size_t b64 = (size_t)64 * ldb;

#define STAGE_A(t, g, b) ldg2lds16(gA + ((size_t)(t) << 6) + (size_t)(g) * a64, \
                                   &sA[b][(g) * 4096 + tid * 8])
#define STAGE_B(t, g, b) ldg2lds16(gB + ((size_t)(t) << 6) + (size_t)(g) * b64, \
                                   &sB[b][(g) * 4096 + tid * 8])
#define PHASE_END() do { __builtin_amdgcn_sched_barrier(0); \
                         __builtin_amdgcn_s_barrier(); } while (0)

  // reader side of the swizzle
  const int fr = lane & 15;
  const int fq = lane >> 4;
  const int p0 = (fq ^ (fr & 7)) * 8;
  const int p1 = p0 ^ 32;
  const int wm = (wave & 1) * 128;   // per-wave rows: wm..wm+127
  const int wn = (wave >> 1) * 64;   // per-wave cols: wn..wn+63

  const int NT = Keff >> 6;

  // --- prologue: tile0 full (8 loads oldest), tile1 partial (6 loads) ---
  STAGE_A(0, 0, 0); STAGE_A(0, 1, 0); STAGE_A(0, 2, 0); STAGE_A(0, 3, 0);
  STAGE_B(0, 0, 0); STAGE_B(0, 1, 0); STAGE_B(0, 2, 0); STAGE_B(0, 3, 0);
  if (NT > 1) {
    STAGE_A(1, 0, 1); STAGE_A(1, 2, 1);
    STAGE_B(1, 0, 1); STAGE_B(1, 1, 1); STAGE_B(1, 2, 1); STAGE_B(1, 3, 1);
    asm volatile("s_waitcnt vmcnt(6)" ::: "memory");
  } else {
    asm volatile("s_waitcnt vmcnt(0)" ::: "memory");
  }
  __builtin_amdgcn_s_barrier();

  f32x4 acc[8][4] = {};

  for (int t = 0; t < NT; ++t) {
    const int bu = t & 1, nx = bu ^ 1;
    const bf16* rA = &sA[bu][(wm + fr) * 64];
    const bf16* rB = &sB[bu][(wn + fr) * 64];
    bf16x8 a0[4], a1[4], bl0[2], bl1[2], bh0[2], bh1[2];

    // ---- phase 0: stage A-g1,g3(t+1)->nx; read A-lo(8)+B-lo(4); MFMA q(0,0)
    if (t + 1 < NT) { STAGE_A(t + 1, 1, nx); STAGE_A(t + 1, 3, nx); }
#pragma unroll
    for (int i = 0; i < 4; ++i) {
      a0[i] = *(const bf16x8*)(rA + i * 1024 + p0);
      a1[i] = *(const bf16x8*)(rA + i * 1024 + p1);
    }
#pragma unroll
    for (int j = 0; j < 2; ++j) {
      bl0[j] = *(const bf16x8*)(rB + j * 1024 + p0);
      bl1[j] = *(const bf16x8*)(rB + j * 1024 + p1);
    }
    __builtin_amdgcn_s_setprio(1);
#pragma unroll
    for (int i = 0; i < 4; ++i)
#pragma unroll
      for (int j = 0; j < 2; ++j) {
        acc[i][j] = __builtin_amdgcn_mfma_f32_16x16x32_bf16(a0[i], bl0[j], acc[i][j], 0, 0, 0);
        acc[i][j] = __builtin_amdgcn_mfma_f32_16x16x32_bf16(a1[i], bl1[j], acc[i][j], 0, 0, 0);
      }
    __builtin_amdgcn_s_setprio(0);
    PHASE_END();

    // ---- phase 1: stage A-g0,g2(t+2)->bu (retired ph0); read B-hi(4);
    //      MFMA q(0,1) (A-lo held in regs)
    if (t + 2 < NT) { STAGE_A(t + 2, 0, bu); STAGE_A(t + 2, 2, bu); }
#pragma unroll
    for (int j = 0; j < 2; ++j) {
      bh0[j] = *(const bf16x8*)(rB + (2 + j) * 1024 + p0);
      bh1[j] = *(const bf16x8*)(rB + (2 + j) * 1024 + p1);
    }
    __builtin_amdgcn_s_setprio(1);
#pragma unroll
    for (int i = 0; i < 4; ++i)
#pragma unroll
      for (int j = 0; j < 2; ++j) {
        acc[i][2 + j] = __builtin_amdgcn_mfma_f32_16x16x32_bf16(a0[i], bh0[j], acc[i][2 + j], 0, 0, 0);
        acc[i][2 + j] = __builtin_amdgcn_mfma_f32_16x16x32_bf16(a1[i], bh1[j], acc[i][2 + j], 0, 0, 0);
      }
    __builtin_amdgcn_s_setprio(0);
    PHASE_END();

    // ---- phase 2: stage B-g0,g1(t+2)->bu (retired ph0); read A-hi(8);
    //      MFMA q(1,1) (B-hi held)
    if (t + 2 < NT) { STAGE_B(t + 2, 0, bu); STAGE_B(t + 2, 1, bu); }
#pragma unroll
    for (int i = 0; i < 4; ++i) {
      a0[i] = *(const bf16x8*)(rA + 4096 + i * 1024 + p0);
      a1[i] = *(const bf16x8*)(rA + 4096 + i * 1024 + p1);
    }
    __builtin_amdgcn_s_setprio(1);
#pragma unroll
    for (int i = 0; i < 4; ++i)
#pragma unroll
      for (int j = 0; j < 2; ++j) {
        acc[4 + i][2 + j] = __builtin_amdgcn_mfma_f32_16x16x32_bf16(a0[i], bh0[j], acc[4 + i][2 + j], 0, 0, 0);
        acc[4 + i][2 + j] = __builtin_amdgcn_mfma_f32_16x16x32_bf16(a1[i], bh1[j], acc[4 + i][2 + j], 0, 0, 0);
      }
    __builtin_amdgcn_s_setprio(0);
    PHASE_END();

    // ---- phase 3: stage B-g2,g3(t+2)->bu (retired ph1); no reads;
    //      MFMA q(1,0) (A-hi + held B-lo); counted gate.
    if (t + 2 < NT) { STAGE_B(t + 2, 2, bu); STAGE_B(t + 2, 3, bu); }
    __builtin_amdgcn_s_setprio(1);
#pragma unroll
    for (int i = 0; i < 4; ++i)
#pragma unroll
      for (int j = 0; j < 2; ++j) {
        acc[4 + i][j] = __builtin_amdgcn_mfma_f32_16x16x32_bf16(a0[i], bl0[j], acc[4 + i][j], 0, 0, 0);
        acc[4 + i][j] = __builtin_amdgcn_mfma_f32_16x16x32_bf16(a1[i], bl1[j], acc[4 + i][j], 0, 0, 0);
      }
    __builtin_amdgcn_s_setprio(0);
    if (t + 2 < NT) {
      asm volatile("s_waitcnt vmcnt(6)" ::: "memory");
    } else if (t + 1 < NT) {
      asm volatile("s_waitcnt vmcnt(0)" ::: "memory");
    }
    PHASE_END();
  }
#undef STAGE_A
#undef STAGE_B
#undef PHASE_END

  // epilogue: C/D 16x16x32 layout: row = fq*4 + reg, col = fr
  const int er = m0 + wm + fq * 4;
  const int ec = n0 + wn + fr;
  float* const dst6 = (EPI == 6) ? (kh ? Cf2 : Cf) : nullptr;
#pragma unroll
  for (int qm = 0; qm < 2; ++qm) {
#pragma unroll
    for (int i = 0; i < 4; ++i) {
#pragma unroll
      for (int r = 0; r < 4; ++r) {
        const int gr = er + qm * 64 + i * 16 + r;
#pragma unroll
        for (int j = 0; j < 4; ++j) {
          const int gc = ec + j * 16;
          const size_t idx = (size_t)gr * ldc + gc;
          float v = acc[qm * 4 + i][j][r];
          if (EPI == 0) {
            Cb[idx] = (bf16)(v + bias[gc]);
          } else if (EPI == 2) {
            Cb[idx] = (bf16)(v * scale);
          } else if (EPI == 4) {
            v += bias[gc];
            Cb[idx] = (bf16)(v > 0.f ? v : 0.f);
          } else {  // EPI == 6
            dst6[idx] = v;
          }
        }
      }
    }
  }
}

// ---------------------------------------------------------------------------
// combine: out = y0 + y1 [+ bias[col]] [+ addf] [+ (float)addb]; fused LN sums.
__global__ __launch_bounds__(256)
void combine_ln(const float* __restrict__ y0, const float* __restrict__ y1,
                const float* __restrict__ bias, const float* __restrict__ addf,
                const bf16* __restrict__ addb,
                float* __restrict__ out, float* __restrict__ red,
                int colMask, int total4)
{
  float ls = 0.f, ls2 = 0.f;
  for (int idx = blockIdx.x * 256 + threadIdx.x; idx < total4;
       idx += gridDim.x * 256) {
    const size_t i = (size_t)idx * 4;
    const float4 u0 = *(const float4*)(y0 + i);
    const float4 u1 = *(const float4*)(y1 + i);
    float vx = u0.x + u1.x, vy = u0.y + u1.y, vz = u0.z + u1.z, vw = u0.w + u1.w;
    if (bias) {
      const float4 b = *(const float4*)(bias + (int)(i & colMask));
      vx += b.x; vy += b.y; vz += b.z; vw += b.w;
    }
    if (addf) {
      const float4 a = *(const float4*)(addf + i);
      vx += a.x; vy += a.y; vz += a.z; vw += a.w;
    }
    if (addb) {
      const bf16x4 a = *(const bf16x4*)(addb + i);
      vx += (float)a[0]; vy += (float)a[1]; vz += (float)a[2]; vw += (float)a[3];
    }
    float4 o; o.x = vx; o.y = vy; o.z = vz; o.w = vw;
    *(float4*)(out + i) = o;
    ls  += vx + vy + vz + vw;
    ls2 += vx * vx + vy * vy + vz * vz + vw * vw;
  }
#pragma unroll
  for (int o = 32; o; o >>= 1) {
    ls  += __shfl_xor(ls,  o, 64);
    ls2 += __shfl_xor(ls2, o, 64);
  }
  __shared__ float sr[8];
  const int lane = threadIdx.x & 63, wave = threadIdx.x >> 6;
  if (lane == 0) { sr[wave * 2] = ls; sr[wave * 2 + 1] = ls2; }
  __syncthreads();
  if (threadIdx.x == 0) {
    atomicAdd(red,     sr[0] + sr[2] + sr[4] + sr[6]);
    atomicAdd(red + 1, sr[1] + sr[3] + sr[5] + sr[7]);
  }
}

// out bf16 = p0 + p1 + bias[row], row = (idx*4) / (1<<(shift+2))
__global__ __launch_bounds__(256)
void combine_bias_row(const float* __restrict__ p0, const float* __restrict__ p1,
                      const float* __restrict__ bias, bf16* __restrict__ outb,
                      int shift, int total4)
{
  for (int idx = blockIdx.x * 256 + threadIdx.x; idx < total4;
       idx += gridDim.x * 256) {
    const size_t i = (size_t)idx * 4;
    const float4 u0 = *(const float4*)(p0 + i);
    const float4 u1 = *(const float4*)(p1 + i);
    const float b = bias[idx >> shift];
    bf16x4 o;
    o[0] = (bf16)(u0.x + u1.x + b);
    o[1] = (bf16)(u0.y + u1.y + b);
    o[2] = (bf16)(u0.z + u1.z + b);
    o[3] = (bf16)(u0.w + u1.w + b);
    *(bf16x4*)(outb + i) = o;
  }
}

// ---------------------------------------------------------------------------
__global__ __launch_bounds__(256)
void cvt_f32_bf16(const float* __restrict__ src, bf16* __restrict__ dst)
{
  const size_t i = ((size_t)blockIdx.x * 256 + threadIdx.x) * 4;
  const float4 t = *(const float4*)(src + i);
  bf16x4 b;
  b[0] = (bf16)t.x; b[1] = (bf16)t.y; b[2] = (bf16)t.z; b[3] = (bf16)t.w;
  *(bf16x4*)(dst + i) = b;
}

// fp32 [R,C] -> bf16 [C,R]
__global__ __launch_bounds__(256)
void transpose_cvt(const float* __restrict__ src, bf16* __restrict__ dst, int R, int C)
{
  __shared__ float tile[32][33];
  const int c0 = blockIdx.x * 32, r0 = blockIdx.y * 32;
  const int tx = threadIdx.x & 31, ty = threadIdx.x >> 5;
#pragma unroll
  for (int rr = ty; rr < 32; rr += 8)
    tile[rr][tx] = src[(size_t)(r0 + rr) * C + (c0 + tx)];
  __syncthreads();
#pragma unroll
  for (int rr = ty; rr < 32; rr += 8)
    dst[(size_t)(c0 + rr) * R + (r0 + tx)] = (bf16)tile[tx][rr];
}

__global__ __launch_bounds__(256)
void concat_bias(const float* __restrict__ a, const float* __restrict__ b,
                 float* __restrict__ o)
{
  const int i = blockIdx.x * 256 + threadIdx.x;   // grid 16 -> 4096
  o[i] = (i < 2048) ? a[i] : b[i - 2048];
}

// ---------------------------------------------------------------------------
__global__ __launch_bounds__(256)
void softmax_rows(bf16* __restrict__ P)
{
  const int row  = blockIdx.x;
  bf16* p = P + (size_t)row * 4096;
  const int tid  = threadIdx.x;
  const int lane = tid & 63, wave = tid >> 6;

  bf16x8 c0 = *(const bf16x8*)(p + tid * 16);
  bf16x8 c1 = *(const bf16x8*)(p + tid * 16 + 8);
  float v[16];
#pragma unroll
  for (int i = 0; i < 8; ++i) { v[i] = (float)c0[i]; v[8 + i] = (float)c1[i]; }

  float m = v[0];
#pragma unroll
  for (int i = 1; i < 16; ++i) m = fmaxf(m, v[i]);
#pragma unroll
  for (int o = 32; o; o >>= 1) m = fmaxf(m, __shfl_xor(m, o, 64));
  __shared__ float sred[8];
  if (lane == 0) sred[wave] = m;
  __syncthreads();
  m = fmaxf(fmaxf(sred[0], sred[1]), fmaxf(sred[2], sred[3]));

  float s = 0.f;
#pragma unroll
  for (int i = 0; i < 16; ++i) { v[i] = __expf(v[i] - m); s += v[i]; }
#pragma unroll
  for (int o = 32; o; o >>= 1) s += __shfl_xor(s, o, 64);
  if (lane == 0) sred[4 + wave] = s;
  __syncthreads();
  s = sred[4] + sred[5] + sred[6] + sred[7];

  const float inv = 1.f / s;
  bf16x8 o0, o1;
#pragma unroll
  for (int i = 0; i < 8; ++i) { o0[i] = (bf16)(v[i] * inv); o1[i] = (bf16)(v[8 + i] * inv); }
  *(bf16x8*)(p + tid * 16)     = o0;
  *(bf16x8*)(p + tid * 16 + 8) = o1;
}

// ---------------------------------------------------------------------------
__global__ void ln_finalize(float* red, float n)
{
  const float mu  = red[0] / n;
  const float var = red[1] / n - mu * mu;
  red[2] = mu;
  red[3] = rsqrtf(var + 1e-5f);
}

__global__ __launch_bounds__(256)
void ln_apply(const float* __restrict__ y, const float* __restrict__ red,
              float* __restrict__ of, bf16* __restrict__ ob)
{
  const float mu = red[2], rs = red[3];
  const size_t i = ((size_t)blockIdx.x * 256 + threadIdx.x) * 4;
  float4 t = *(const float4*)(y + i);
  t.x = (t.x - mu) * rs; t.y = (t.y - mu) * rs;
  t.z = (t.z - mu) * rs; t.w = (t.w - mu) * rs;
  if (of) *(float4*)(of + i) = t;
  if (ob) {
    bf16x4 b;
    b[0] = (bf16)t.x; b[1] = (bf16)t.y; b[2] = (bf16)t.z; b[3] = (bf16)t.w;
    *(bf16x4*)(ob + i) = b;
  }
}

// ---------------------------------------------------------------------------
extern "C" void kernel_launch(void* const* d_in, const int* in_sizes, int n_in,
                              void* d_out, int out_size, void* d_ws, size_t ws_size,
                              hipStream_t stream)
{
  const float* x  = (const float*)d_in[0];
  const float* Wq = (const float*)d_in[1];
  const float* bq = (const float*)d_in[2];
  const float* Wk = (const float*)d_in[3];
  const float* bk = (const float*)d_in[4];
  const float* Wv = (const float*)d_in[5];
  const float* bv = (const float*)d_in[6];
  const float* W1 = (const float*)d_in[7];
  const float* b1 = (const float*)d_in[8];
  const float* W2 = (const float*)d_in[9];
  const float* b2 = (const float*)d_in[10];
  float* out = (float*)d_out;

  const size_t MB = 1ull << 20;
  char* ws = (char*)d_ws;

  // Layout (peak 216 MB + small tail):
  //   0- 16: xb / hb (bf16)
  //  16- 32: WqkT [4096,2048] bf16  (rows 0-2047 Wq^T, 2048-4095 Wk^T)
  //  32- 40: WvT   40- 72: W1T   72-104: W2T
  // 104-136: QKb [S,4096] bf16; later: y1_pv (f32) / act[0:32MB]
  // 136-168: Pb [S,S] bf16; V-split partial half1 before scores; act[32:64MB]
  // 168-184: VbT
  // 184-216: y (f32; also V-split partial half0 before attn)
  //  16- 48: y1_f2 (f32) during FFN2 (over dead WqkT/WvT/W1T-head)
  // 216+   : red (8 f), bqk (4096 f)
  bf16*  xb   = (bf16*)(ws);
  bf16*  hb   = xb;
  bf16*  WqkT = (bf16*)(ws + 16 * MB);
  bf16*  WvT  = (bf16*)(ws + 32 * MB);
  bf16*  W1T  = (bf16*)(ws + 40 * MB);
  bf16*  W2T  = (bf16*)(ws + 72 * MB);
  bf16*  QKb  = (bf16*)(ws + 104 * MB);
  float* y1pv = (float*)(ws + 104 * MB);
  bf16*  Pb   = (bf16*)(ws + 136 * MB);
  float* vph1 = (float*)(ws + 136 * MB);
  bf16*  act  = (bf16*)(ws + 104 * MB);
  bf16*  VbT  = (bf16*)(ws + 168 * MB);
  float* y    = (float*)(ws + 184 * MB);
  float* vph0 = (float*)(ws + 184 * MB);
  float* y1f2 = (float*)(ws + 16 * MB);
  float* red  = (float*)(ws + 216 * MB);
  float* bqk  = (float*)(ws + 216 * MB + 4096);

  hipMemsetAsync(red, 0, 32, stream);

  const dim3 blk(256);
  const dim3 blkg(512);
  const int nElemBlocks = (S * E) / 1024;
  const int total4 = (S * E) / 4;

  cvt_f32_bf16<<<dim3(nElemBlocks), blk, 0, stream>>>(x, xb);
  transpose_cvt<<<dim3(E / 32, E / 32), blk, 0, stream>>>(Wq, WqkT, E, E);
  transpose_cvt<<<dim3(E / 32, E / 32), blk, 0, stream>>>(Wk, WqkT + (size_t)E * E, E, E);
  transpose_cvt<<<dim3(E / 32, E / 32), blk, 0, stream>>>(Wv, WvT, E, E);
  transpose_cvt<<<dim3(H / 32, E / 32), blk, 0, stream>>>(W1, W1T, E, H);
  transpose_cvt<<<dim3(E / 32, H / 32), blk, 0, stream>>>(W2, W2T, H, E);
  concat_bias<<<dim3(16), blk, 0, stream>>>(bq, bk, bqk);

  // merged [Q|K] = x @ [Wq|Wk] + [bq|bk]  (256 WGs, full chip)
  gemm256<0, false><<<dim3(4096 / 256, S / 256), blkg, 0, stream>>>(
      xb, E, WqkT, E, QKb, nullptr, nullptr, 4096, bqk, S, 4096, E, 0.f);

  // V^T[E,S] = WvT @ x^T + bv[row], split-K x2 (256 WGs) + row-bias combine
  gemm256<6, true><<<dim3(S / 256, (E / 256) * 2), blkg, 0, stream>>>(
      WvT, E, xb, E, nullptr, vph0, vph1, S, nullptr, E, S, E, 0.f);
  combine_bias_row<<<dim3(2048), blk, 0, stream>>>(
      vph0, vph1, bv, VbT, 10, (E * S) / 4);

  // scores = (Q @ K^T)/64 -> bf16, softmax rows  (256 WGs)
  gemm256<2, false><<<dim3(S / 256, S / 256), blkg, 0, stream>>>(
      QKb, 4096, QKb + 2048, 4096, Pb, nullptr, nullptr, S, nullptr,
      S, S, E, 1.0f / 64.0f);
  softmax_rows<<<dim3(S), blk, 0, stream>>>(Pb);

  // P @ V split-K x2 -> partials (256 WGs), combine + x + LN sums
  gemm256<6, true><<<dim3(E / 256, (S / 256) * 2), blkg, 0, stream>>>(
      Pb, S, VbT, S, nullptr, y, y1pv, E, nullptr, S, E, S, 0.f);
  combine_ln<<<dim3(2048), blk, 0, stream>>>(
      y, y1pv, nullptr, x, nullptr, y, red, E - 1, total4);
  ln_finalize<<<1, 1, 0, stream>>>(red, (float)((size_t)S * E));
  ln_apply<<<dim3(nElemBlocks), blk, 0, stream>>>(y, red, nullptr, hb);

  // act = relu(h @ W1 + b1)  (512 WGs)
  gemm256<4, false><<<dim3(H / 256, S / 256), blkg, 0, stream>>>(
      hb, E, W1T, E, act, nullptr, nullptr, H, b1, S, H, E, 0.f);

  // act @ W2 split-K x2 -> partials, combine + b2 + h + LN sums
  gemm256<6, true><<<dim3(E / 256, (S / 256) * 2), blkg, 0, stream>>>(
      act, H, W2T, H, nullptr, y, y1f2, E, nullptr, S, E, H, 0.f);
  combine_ln<<<dim3(2048), blk, 0, stream>>>(
      y, y1f2, b2, nullptr, hb, y, red + 4, E - 1, total4);
  ln_finalize<<<1, 1, 0, stream>>>(red + 4, (float)((size_t)S * E));
  ln_apply<<<dim3(nElemBlocks), blk, 0, stream>>>(y, red + 4, out, nullptr);
}

// Round 6
// 880.981 us; speedup vs baseline: 1.2263x; 1.2263x over previous
//
#include <hip/hip_runtime.h>
#include <cstdint>
#include <cstddef>

// ---------------------------------------------------------------------------
// EncoderBlock: S=4096, E=2048, H=8192, fp32 in/out, bf16 MFMA internally.
// R8 (resubmit; R5 bench was an infra container failure, kernel never ran):
//   - gemm256: R6's proven 256^2 schedule (two barriers/phase, lgkmcnt(0)
//     drain before each 16-MFMA burst, setprio(1) around MFMA, one counted
//     vmcnt(6) gate per K-tile). K-loop unrolled x2 -> static buffer indices
//     (template's "8 phases / 2 K-tiles per iter" form). Used where 256^2
//     fills the chip: merged-QK (256 WG), scores (256 WG), FFN1 (512 WG).
//   - gemm_bt: R4's proven 128^2 kernel, verbatim (773 TF, 3 blocks/CU,
//     fused epilogues). Used where 256^2 cannot fill the chip: V^T (512 WG),
//     PV + x-residual + LN sums (512 WG), FFN2 + bias + h-residual + LN
//     sums (512 WG). No split-K, no combine kernels, no partial buffers.
// ---------------------------------------------------------------------------

constexpr int S = 4096;
constexpr int E = 2048;
constexpr int H = 8192;

typedef __bf16 bf16;
typedef bf16  bf16x8 __attribute__((ext_vector_type(8)));
typedef bf16  bf16x4 __attribute__((ext_vector_type(4)));
typedef float f32x4  __attribute__((ext_vector_type(4)));

typedef __attribute__((address_space(1))) void as1_void;
typedef __attribute__((address_space(3))) void as3_void;

__device__ __forceinline__ void ldg2lds16(const void* g, void* l) {
  __builtin_amdgcn_global_load_lds((as1_void*)g, (as3_void*)l, 16, 0, 0);
}

// ---------------------------------------------------------------------------
// gemm256: C[M,N] = A[M,K] @ Bt[N,K]^T. Tile 256x256, BK=64, 8 waves.
// EPI 0: out bf16 = acc + bias[col]        (merged QK proj)
// EPI 2: out bf16 = acc * scale            (scores)
// EPI 4: out bf16 = relu(acc + bias[col])  (FFN act)
// Requires M%256==0, N%256==0, K%128==0 (NT even), NT>=4, nwg%8==0.
// ---------------------------------------------------------------------------
template <int EPI>
__global__ __launch_bounds__(512, 2)
void gemm256(const bf16* __restrict__ A, int lda,
             const bf16* __restrict__ Bt, int ldb,
             bf16* __restrict__ Cb, int ldc,
             const float* __restrict__ bias,
             int M, int N, int K, float scale)
{
  __shared__ bf16 sA[2][256 * 64];   // 64 KB
  __shared__ bf16 sB[2][256 * 64];   // 64 KB

  const int tid  = threadIdx.x;
  const int lane = tid & 63;
  const int wave = tid >> 6;

  // XCD-chunked swizzle (nwg % 8 == 0 -> bijective)
  const int nbx = gridDim.x;
  const int nwg = nbx * gridDim.y;
  const int bid = blockIdx.y * nbx + blockIdx.x;
  const int wg  = (bid & 7) * (nwg >> 3) + (bid >> 3);
  const int m0  = (wg / nbx) * 256;
  const int n0  = (wg % nbx) * 256;

  // staging: thread covers row tr (0..63) of a 64-row group, 16B chunk tc.
  // Global chunk XOR-swizzled by (row&7); LDS stays linear (gload_lds rule).
  const int tr  = tid >> 3;
  const int tc  = tid & 7;
  const int gsw = (tc ^ (tr & 7)) * 8;
  const bf16* gA = A  + (size_t)(m0 + tr) * lda + gsw;
  const bf16* gB = Bt + (size_t)(n0 + tr) * ldb + gsw;
  const size_t a64 = (size_t)64 * lda;
  const size_t b64 = (size_t)64 * ldb;

#define STAGE_A(t, g, b) ldg2lds16(gA + ((size_t)(t) << 6) + (size_t)(g) * a64, \
                                   &sA[b][(g) * 4096 + tid * 8])
#define STAGE_B(t, g, b) ldg2lds16(gB + ((size_t)(t) << 6) + (size_t)(g) * b64, \
                                   &sB[b][(g) * 4096 + tid * 8])

  // reader side of the swizzle
  const int fr = lane & 15;
  const int fq = lane >> 4;
  const int p0 = (fq ^ (fr & 7)) * 8;
  const int p1 = p0 ^ 32;
  const int wm = (wave & 1) * 128;   // per-wave rows: wm..wm+127
  const int wn = (wave >> 1) * 64;   // per-wave cols: wn..wn+63

  const int NT = K >> 6;             // even, >= 4

  // --- prologue: tile0 full (8 loads oldest), tile1 partial (6 loads) ---
  STAGE_A(0, 0, 0); STAGE_A(0, 1, 0); STAGE_A(0, 2, 0); STAGE_A(0, 3, 0);
  STAGE_B(0, 0, 0); STAGE_B(0, 1, 0); STAGE_B(0, 2, 0); STAGE_B(0, 3, 0);
  STAGE_A(1, 0, 1); STAGE_A(1, 2, 1);
  STAGE_B(1, 0, 1); STAGE_B(1, 1, 1); STAGE_B(1, 2, 1); STAGE_B(1, 3, 1);
  asm volatile("s_waitcnt vmcnt(6)" ::: "memory");
  __builtin_amdgcn_s_barrier();

  f32x4 acc[8][4] = {};

  // One K-tile with compile-time buffer indices BU (compute) / NX (other).
  // Schedule identical to R6 (two barriers per phase, lgkm(0) drain,
  // setprio around MFMA, reads-then-stage order, vmcnt(6) gate at ph3).
#define KTILE(BU, NX, TT)                                                     \
  {                                                                           \
    const bf16* rA = &sA[BU][(wm + fr) * 64];                                 \
    const bf16* rB = &sB[BU][(wn + fr) * 64];                                 \
    bf16x8 a0[4], a1[4], bl0[2], bl1[2], bh0[2], bh1[2];                      \
    /* ---- phase 0: read A-lo(8)+B-lo(4); stage A-g1,g3(TT+1)->NX ---- */    \
    _Pragma("unroll")                                                         \
    for (int i = 0; i < 4; ++i) {                                             \
      a0[i] = *(const bf16x8*)(rA + i * 1024 + p0);                           \
      a1[i] = *(const bf16x8*)(rA + i * 1024 + p1);                           \
    }                                                                         \
    _Pragma("unroll")                                                         \
    for (int j = 0; j < 2; ++j) {                                             \
      bl0[j] = *(const bf16x8*)(rB + j * 1024 + p0);                          \
      bl1[j] = *(const bf16x8*)(rB + j * 1024 + p1);                          \
    }                                                                         \
    if ((TT) + 1 < NT) { STAGE_A((TT) + 1, 1, NX); STAGE_A((TT) + 1, 3, NX); }\
    __builtin_amdgcn_s_barrier();                                             \
    asm volatile("s_waitcnt lgkmcnt(0)" ::: "memory");                        \
    __builtin_amdgcn_s_setprio(1);                                            \
    _Pragma("unroll")                                                         \
    for (int i = 0; i < 4; ++i)                                               \
      _Pragma("unroll")                                                       \
      for (int j = 0; j < 2; ++j) {                                           \
        acc[i][j] = __builtin_amdgcn_mfma_f32_16x16x32_bf16(a0[i], bl0[j], acc[i][j], 0, 0, 0); \
        acc[i][j] = __builtin_amdgcn_mfma_f32_16x16x32_bf16(a1[i], bl1[j], acc[i][j], 0, 0, 0); \
      }                                                                       \
    __builtin_amdgcn_s_setprio(0);                                            \
    __builtin_amdgcn_s_barrier();                                             \
    /* ---- phase 1: read B-hi(4); stage A-g0,g2(TT+2)->BU ---- */            \
    _Pragma("unroll")                                                         \
    for (int j = 0; j < 2; ++j) {                                             \
      bh0[j] = *(const bf16x8*)(rB + (2 + j) * 1024 + p0);                    \
      bh1[j] = *(const bf16x8*)(rB + (2 + j) * 1024 + p1);                    \
    }                                                                         \
    if ((TT) + 2 < NT) { STAGE_A((TT) + 2, 0, BU); STAGE_A((TT) + 2, 2, BU); }\
    __builtin_amdgcn_s_barrier();                                             \
    asm volatile("s_waitcnt lgkmcnt(0)" ::: "memory");                        \
    __builtin_amdgcn_s_setprio(1);                                            \
    _Pragma("unroll")                                                         \
    for (int i = 0; i < 4; ++i)                                               \
      _Pragma("unroll")                                                       \
      for (int j = 0; j < 2; ++j) {                                           \
        acc[i][2 + j] = __builtin_amdgcn_mfma_f32_16x16x32_bf16(a0[i], bh0[j], acc[i][2 + j], 0, 0, 0); \
        acc[i][2 + j] = __builtin_amdgcn_mfma_f32_16x16x32_bf16(a1[i], bh1[j], acc[i][2 + j], 0, 0, 0); \
      }                                                                       \
    __builtin_amdgcn_s_setprio(0);                                            \
    __builtin_amdgcn_s_barrier();                                             \
    /* ---- phase 2: read A-hi(8); stage B-g0,g1(TT+2)->BU ---- */            \
    _Pragma("unroll")                                                         \
    for (int i = 0; i < 4; ++i) {                                             \
      a0[i] = *(const bf16x8*)(rA + 4096 + i * 1024 + p0);                    \
      a1[i] = *(const bf16x8*)(rA + 4096 + i * 1024 + p1);                    \
    }                                                                         \
    if ((TT) + 2 < NT) { STAGE_B((TT) + 2, 0, BU); STAGE_B((TT) + 2, 1, BU); }\
    __builtin_amdgcn_s_barrier();                                             \
    asm volatile("s_waitcnt lgkmcnt(0)" ::: "memory");                        \
    __builtin_amdgcn_s_setprio(1);                                            \
    _Pragma("unroll")                                                         \
    for (int i = 0; i < 4; ++i)                                               \
      _Pragma("unroll")                                                       \
      for (int j = 0; j < 2; ++j) {                                           \
        acc[4 + i][2 + j] = __builtin_amdgcn_mfma_f32_16x16x32_bf16(a0[i], bh0[j], acc[4 + i][2 + j], 0, 0, 0); \
        acc[4 + i][2 + j] = __builtin_amdgcn_mfma_f32_16x16x32_bf16(a1[i], bh1[j], acc[4 + i][2 + j], 0, 0, 0); \
      }                                                                       \
    __builtin_amdgcn_s_setprio(0);                                            \
    __builtin_amdgcn_s_barrier();                                             \
    /* ---- phase 3: no reads; stage B-g2,g3(TT+2)->BU; counted gate ---- */  \
    if ((TT) + 2 < NT) { STAGE_B((TT) + 2, 2, BU); STAGE_B((TT) + 2, 3, BU); }\
    __builtin_amdgcn_s_barrier();                                             \
    __builtin_amdgcn_s_setprio(1);                                            \
    _Pragma("unroll")                                                         \
    for (int i = 0; i < 4; ++i)                                               \
      _Pragma("unroll")                                                       \
      for (int j = 0; j < 2; ++j) {                                           \
        acc[4 + i][j] = __builtin_amdgcn_mfma_f32_16x16x32_bf16(a0[i], bl0[j], acc[4 + i][j], 0, 0, 0); \
        acc[4 + i][j] = __builtin_amdgcn_mfma_f32_16x16x32_bf16(a1[i], bl1[j], acc[4 + i][j], 0, 0, 0); \
      }                                                                       \
    __builtin_amdgcn_s_setprio(0);                                            \
    if ((TT) + 2 < NT) {                                                      \
      asm volatile("s_waitcnt vmcnt(6)" ::: "memory");                        \
    } else if ((TT) + 1 < NT) {                                               \
      asm volatile("s_waitcnt vmcnt(0)" ::: "memory");                        \
    }                                                                         \
    __builtin_amdgcn_s_barrier();                                             \
  }

  for (int t = 0; t < NT; t += 2) {
    KTILE(0, 1, t);
    KTILE(1, 0, t + 1);
  }
#undef KTILE
#undef STAGE_A
#undef STAGE_B

  // epilogue: C/D 16x16x32 layout: row = fq*4 + reg, col = fr
  const int er = m0 + wm + fq * 4;
  const int ec = n0 + wn + fr;
#pragma unroll
  for (int qm = 0; qm < 2; ++qm) {
#pragma unroll
    for (int i = 0; i < 4; ++i) {
#pragma unroll
      for (int r = 0; r < 4; ++r) {
        const int gr = er + qm * 64 + i * 16 + r;
#pragma unroll
        for (int j = 0; j < 4; ++j) {
          const int gc = ec + j * 16;
          const size_t idx = (size_t)gr * ldc + gc;
          float v = acc[qm * 4 + i][j][r];
          if (EPI == 0) {
            Cb[idx] = (bf16)(v + bias[gc]);
          } else if (EPI == 2) {
            Cb[idx] = (bf16)(v * scale);
          } else {  // EPI == 4
            v += bias[gc];
            Cb[idx] = (bf16)(v > 0.f ? v : 0.f);
          }
        }
      }
    }
  }
}

// ---------------------------------------------------------------------------
// gemm_bt (R4 verbatim): C[M,N] = A[M,K] @ Bt[N,K]^T, 128^2 tile, BK=64.
// EPI 1: out bf16 = acc + bias[row]                   (V^T proj)
// EPI 3: out f32  = acc + add (f32), fused LN sums    (attn residual)
// EPI 5: out f32  = acc + bias[col] + addb (bf16), fused LN sums (FFN resid)
// Requires gridDim.x % 8 == 0, gridDim.y % 8 == 0, K % 64 == 0.
// ---------------------------------------------------------------------------
template <int EPI>
__global__ __launch_bounds__(256, 3)
void gemm_bt(const bf16* __restrict__ A, int lda,
             const bf16* __restrict__ Bt, int ldb,
             bf16* __restrict__ Cb, float* __restrict__ Cf, int ldc,
             const float* __restrict__ bias, const float* __restrict__ add,
             const bf16* __restrict__ addb,
             float* __restrict__ red, int M, int N, int K, float scale)
{
  __shared__ bf16 sA[128 * 64];   // 16 KB
  __shared__ bf16 sB[128 * 64];   // 16 KB

  const int tid  = threadIdx.x;
  const int lane = tid & 63;
  const int wave = tid >> 6;

  // 8x8 super-group swizzle (L2 locality)
  const int ntiles = gridDim.x;
  const int b      = blockIdx.y * ntiles + blockIdx.x;
  const int group  = b >> 6;
  const int within = b & 63;
  const int gpr    = ntiles >> 3;
  const int m0 = ((group / gpr) * 8 + (within >> 3)) * 128;
  const int n0 = ((group % gpr) * 8 + (within & 7)) * 128;

  const int wm = (wave & 1) * 64;
  const int wn = (wave >> 1) * 64;

  const int sr = tid >> 3;                         // 0..31
  const int gsw = ((tid & 7) ^ (sr & 7)) * 8;      // swizzled col offset
  const bf16* gA = A  + (size_t)(m0 + sr) * lda + gsw;
  const bf16* gB = Bt + (size_t)(n0 + sr) * ldb + gsw;
  const size_t a32 = (size_t)32 * lda;
  const size_t b32 = (size_t)32 * ldb;
  bf16* lA = &sA[tid * 8];
  bf16* lB = &sB[tid * 8];

  const int fr = lane & 15;
  const int fq = lane >> 4;
  const int p0 = (fq ^ (fr & 7)) * 8;
  const int p1 = p0 ^ 32;
  const bf16* rA = &sA[(wm + fr) * 64];
  const bf16* rB = &sB[(wn + fr) * 64];

  f32x4 acc[4][4] = {};

  for (int k0 = 0; k0 < K; k0 += 64) {
    ldg2lds16(gA,           lA);
    ldg2lds16(gA +     a32, lA + 32 * 64);
    ldg2lds16(gA + 2 * a32, lA + 64 * 64);
    ldg2lds16(gA + 3 * a32, lA + 96 * 64);
    ldg2lds16(gB,           lB);
    ldg2lds16(gB +     b32, lB + 32 * 64);
    ldg2lds16(gB + 2 * b32, lB + 64 * 64);
    ldg2lds16(gB + 3 * b32, lB + 96 * 64);
    gA += 64; gB += 64;
    __syncthreads();   // drains vmcnt(0): staged tiles visible

    bf16x8 a0[4], a1[4], b0[4], b1[4];
#pragma unroll
    for (int i = 0; i < 4; ++i) {
      a0[i] = *(const bf16x8*)(rA + i * 1024 + p0);
      a1[i] = *(const bf16x8*)(rA + i * 1024 + p1);
    }
#pragma unroll
    for (int j = 0; j < 4; ++j) {
      b0[j] = *(const bf16x8*)(rB + j * 1024 + p0);
      b1[j] = *(const bf16x8*)(rB + j * 1024 + p1);
    }
#pragma unroll
    for (int i = 0; i < 4; ++i)
#pragma unroll
      for (int j = 0; j < 4; ++j)
        acc[i][j] = __builtin_amdgcn_mfma_f32_16x16x32_bf16(a0[i], b0[j], acc[i][j], 0, 0, 0);
#pragma unroll
    for (int i = 0; i < 4; ++i)
#pragma unroll
      for (int j = 0; j < 4; ++j)
        acc[i][j] = __builtin_amdgcn_mfma_f32_16x16x32_bf16(a1[i], b1[j], acc[i][j], 0, 0, 0);
    __syncthreads();   // reads done before next iteration overwrites LDS
  }

  const int er = m0 + wm + fq * 4;
  const int ec = n0 + wn + fr;
  float ls = 0.f, ls2 = 0.f;
#pragma unroll
  for (int i = 0; i < 4; ++i) {
#pragma unroll
    for (int r = 0; r < 4; ++r) {
      const int gr = er + i * 16 + r;
#pragma unroll
      for (int j = 0; j < 4; ++j) {
        const int gc = ec + j * 16;
        const size_t idx = (size_t)gr * ldc + gc;
        float v = acc[i][j][r];
        if (EPI == 0) {
          v += bias[gc];
          Cb[idx] = (bf16)v;
        } else if (EPI == 1) {
          v += bias[gr];
          Cb[idx] = (bf16)v;
        } else if (EPI == 2) {
          Cb[idx] = (bf16)(v * scale);
        } else if (EPI == 3) {
          v += add[idx];
          Cf[idx] = v; ls += v; ls2 += v * v;
        } else if (EPI == 4) {
          v += bias[gc];
          v = v > 0.f ? v : 0.f;
          Cb[idx] = (bf16)v;
        } else {  // EPI == 5
          v += bias[gc] + (float)addb[idx];
          Cf[idx] = v; ls += v; ls2 += v * v;
        }
      }
    }
  }

  if (EPI == 3 || EPI == 5) {
#pragma unroll
    for (int o = 32; o; o >>= 1) {
      ls  += __shfl_xor(ls,  o, 64);
      ls2 += __shfl_xor(ls2, o, 64);
    }
    float* sred = (float*)sA;   // safe: all waves past final barrier
    if (lane == 0) { sred[wave * 2] = ls; sred[wave * 2 + 1] = ls2; }
    __syncthreads();
    if (tid == 0) {
      atomicAdd(red,     sred[0] + sred[2] + sred[4] + sred[6]);
      atomicAdd(red + 1, sred[1] + sred[3] + sred[5] + sred[7]);
    }
  }
}

// ---------------------------------------------------------------------------
__global__ __launch_bounds__(256)
void cvt_f32_bf16(const float* __restrict__ src, bf16* __restrict__ dst)
{
  const size_t i = ((size_t)blockIdx.x * 256 + threadIdx.x) * 4;
  const float4 t = *(const float4*)(src + i);
  bf16x4 b;
  b[0] = (bf16)t.x; b[1] = (bf16)t.y; b[2] = (bf16)t.z; b[3] = (bf16)t.w;
  *(bf16x4*)(dst + i) = b;
}

// fp32 [R,C] -> bf16 [C,R]
__global__ __launch_bounds__(256)
void transpose_cvt(const float* __restrict__ src, bf16* __restrict__ dst, int R, int C)
{
  __shared__ float tile[32][33];
  const int c0 = blockIdx.x * 32, r0 = blockIdx.y * 32;
  const int tx = threadIdx.x & 31, ty = threadIdx.x >> 5;
#pragma unroll
  for (int rr = ty; rr < 32; rr += 8)
    tile[rr][tx] = src[(size_t)(r0 + rr) * C + (c0 + tx)];
  __syncthreads();
#pragma unroll
  for (int rr = ty; rr < 32; rr += 8)
    dst[(size_t)(c0 + rr) * R + (r0 + tx)] = (bf16)tile[tx][rr];
}

__global__ __launch_bounds__(256)
void concat_bias(const float* __restrict__ a, const float* __restrict__ b,
                 float* __restrict__ o)
{
  const int i = blockIdx.x * 256 + threadIdx.x;   // grid 16 -> 4096
  o[i] = (i < 2048) ? a[i] : b[i - 2048];
}

// ---------------------------------------------------------------------------
__global__ __launch_bounds__(256)
void softmax_rows(bf16* __restrict__ P)
{
  const int row  = blockIdx.x;
  bf16* p = P + (size_t)row * 4096;
  const int tid  = threadIdx.x;
  const int lane = tid & 63, wave = tid >> 6;

  bf16x8 c0 = *(const bf16x8*)(p + tid * 16);
  bf16x8 c1 = *(const bf16x8*)(p + tid * 16 + 8);
  float v[16];
#pragma unroll
  for (int i = 0; i < 8; ++i) { v[i] = (float)c0[i]; v[8 + i] = (float)c1[i]; }

  float m = v[0];
#pragma unroll
  for (int i = 1; i < 16; ++i) m = fmaxf(m, v[i]);
#pragma unroll
  for (int o = 32; o; o >>= 1) m = fmaxf(m, __shfl_xor(m, o, 64));
  __shared__ float sred[8];
  if (lane == 0) sred[wave] = m;
  __syncthreads();
  m = fmaxf(fmaxf(sred[0], sred[1]), fmaxf(sred[2], sred[3]));

  float s = 0.f;
#pragma unroll
  for (int i = 0; i < 16; ++i) { v[i] = __expf(v[i] - m); s += v[i]; }
#pragma unroll
  for (int o = 32; o; o >>= 1) s += __shfl_xor(s, o, 64);
  if (lane == 0) sred[4 + wave] = s;
  __syncthreads();
  s = sred[4] + sred[5] + sred[6] + sred[7];

  const float inv = 1.f / s;
  bf16x8 o0, o1;
#pragma unroll
  for (int i = 0; i < 8; ++i) { o0[i] = (bf16)(v[i] * inv); o1[i] = (bf16)(v[8 + i] * inv); }
  *(bf16x8*)(p + tid * 16)     = o0;
  *(bf16x8*)(p + tid * 16 + 8) = o1;
}

// ---------------------------------------------------------------------------
__global__ void ln_finalize(float* red, float n)
{
  const float mu  = red[0] / n;
  const float var = red[1] / n - mu * mu;
  red[2] = mu;
  red[3] = rsqrtf(var + 1e-5f);
}

__global__ __launch_bounds__(256)
void ln_apply(const float* __restrict__ y, const float* __restrict__ red,
              float* __restrict__ of, bf16* __restrict__ ob)
{
  const float mu = red[2], rs = red[3];
  const size_t i = ((size_t)blockIdx.x * 256 + threadIdx.x) * 4;
  float4 t = *(const float4*)(y + i);
  t.x = (t.x - mu) * rs; t.y = (t.y - mu) * rs;
  t.z = (t.z - mu) * rs; t.w = (t.w - mu) * rs;
  if (of) *(float4*)(of + i) = t;
  if (ob) {
    bf16x4 b;
    b[0] = (bf16)t.x; b[1] = (bf16)t.y; b[2] = (bf16)t.z; b[3] = (bf16)t.w;
    *(bf16x4*)(ob + i) = b;
  }
}

// ---------------------------------------------------------------------------
extern "C" void kernel_launch(void* const* d_in, const int* in_sizes, int n_in,
                              void* d_out, int out_size, void* d_ws, size_t ws_size,
                              hipStream_t stream)
{
  const float* x  = (const float*)d_in[0];
  const float* Wq = (const float*)d_in[1];
  const float* bq = (const float*)d_in[2];
  const float* Wk = (const float*)d_in[3];
  const float* bk = (const float*)d_in[4];
  const float* Wv = (const float*)d_in[5];
  const float* bv = (const float*)d_in[6];
  const float* W1 = (const float*)d_in[7];
  const float* b1 = (const float*)d_in[8];
  const float* W2 = (const float*)d_in[9];
  const float* b2 = (const float*)d_in[10];
  float* out = (float*)d_out;

  const size_t MB = 1ull << 20;
  char* ws = (char*)d_ws;

  // Layout (peak 216 MB + tail):
  //   0- 16: xb / hb (bf16)
  //  16- 32: WqkT [4096,2048] bf16  (rows 0-2047 Wq^T, 2048-4095 Wk^T)
  //  32- 40: WvT   40- 72: W1T   72-104: W2T
  // 104-136: QKb [S,4096] bf16 (Qb=base, Kb=base+2048); reused as act[0:32]
  // 136-168: Pb [S,S] bf16; reused as act[32:64]
  // 168-184: VbT
  // 184-216: y (fp32; attn out, then FFN2 out)
  // 216+   : red (8 f), bqk (4096 f)
  bf16*  xb   = (bf16*)(ws);
  bf16*  hb   = xb;
  bf16*  WqkT = (bf16*)(ws + 16 * MB);
  bf16*  WvT  = (bf16*)(ws + 32 * MB);
  bf16*  W1T  = (bf16*)(ws + 40 * MB);
  bf16*  W2T  = (bf16*)(ws + 72 * MB);
  bf16*  QKb  = (bf16*)(ws + 104 * MB);
  bf16*  Pb   = (bf16*)(ws + 136 * MB);
  bf16*  act  = (bf16*)(ws + 104 * MB);
  bf16*  VbT  = (bf16*)(ws + 168 * MB);
  float* y    = (float*)(ws + 184 * MB);
  float* red  = (float*)(ws + 216 * MB);
  float* bqk  = (float*)(ws + 216 * MB + 4096);

  hipMemsetAsync(red, 0, 32, stream);

  const dim3 blk(256);
  const dim3 blkg(512);
  const int nElemBlocks = (S * E) / 1024;

  cvt_f32_bf16<<<dim3(nElemBlocks), blk, 0, stream>>>(x, xb);
  transpose_cvt<<<dim3(E / 32, E / 32), blk, 0, stream>>>(Wq, WqkT, E, E);
  transpose_cvt<<<dim3(E / 32, E / 32), blk, 0, stream>>>(Wk, WqkT + (size_t)E * E, E, E);
  transpose_cvt<<<dim3(E / 32, E / 32), blk, 0, stream>>>(Wv, WvT, E, E);
  transpose_cvt<<<dim3(H / 32, E / 32), blk, 0, stream>>>(W1, W1T, E, H);
  transpose_cvt<<<dim3(E / 32, H / 32), blk, 0, stream>>>(W2, W2T, H, E);
  concat_bias<<<dim3(16), blk, 0, stream>>>(bq, bk, bqk);

  // merged [Q|K] = x @ [Wq|Wk] + [bq|bk]  (256 WGs, gemm256)
  gemm256<0><<<dim3(4096 / 256, S / 256), blkg, 0, stream>>>(
      xb, E, WqkT, E, QKb, 4096, bqk, S, 4096, E, 0.f);

  // V^T[E,S] = WvT @ x^T + bv[row]  (512 WGs, gemm_bt)
  gemm_bt<1><<<dim3(S / 128, E / 128), blk, 0, stream>>>(
      WvT, E, xb, E, VbT, nullptr, S, bv, nullptr, nullptr, nullptr, E, S, E, 0.f);

  // scores = (Q @ K^T)/64 -> bf16, softmax rows  (256 WGs, gemm256)
  gemm256<2><<<dim3(S / 256, S / 256), blkg, 0, stream>>>(
      QKb, 4096, QKb + 2048, 4096, Pb, S, nullptr, S, S, E, 1.0f / 64.0f);
  softmax_rows<<<dim3(S), blk, 0, stream>>>(Pb);

  // y = x + P @ V (fp32, fused LN1 sums)  (512 WGs, gemm_bt)
  gemm_bt<3><<<dim3(E / 128, S / 128), blk, 0, stream>>>(
      Pb, S, VbT, S, nullptr, y, E, nullptr, x, nullptr, red, S, E, S, 0.f);
  ln_finalize<<<1, 1, 0, stream>>>(red, (float)((size_t)S * E));
  ln_apply<<<dim3(nElemBlocks), blk, 0, stream>>>(y, red, nullptr, hb);

  // act = relu(h @ W1 + b1)  (512 WGs, gemm256)
  gemm256<4><<<dim3(H / 256, S / 256), blkg, 0, stream>>>(
      hb, E, W1T, E, act, H, b1, S, H, E, 0.f);

  // y = h + act @ W2 + b2 (fp32, fused LN2 sums)  (512 WGs, gemm_bt)
  gemm_bt<5><<<dim3(E / 128, S / 128), blk, 0, stream>>>(
      act, H, W2T, H, nullptr, y, E, b2, nullptr, hb, red + 4, S, E, H, 0.f);
  ln_finalize<<<1, 1, 0, stream>>>(red + 4, (float)((size_t)S * E));
  ln_apply<<<dim3(nElemBlocks), blk, 0, stream>>>(y, red + 4, out, nullptr);
}